// Round 6
// baseline (618.985 us; speedup 1.0000x reference)
//
#include <hip/hip_runtime.h>
#include <stdint.h>

using u16 = unsigned short;
using u32 = unsigned int;

typedef __attribute__((ext_vector_type(8))) short s16x8;
typedef __attribute__((ext_vector_type(4))) float f32x4;

__device__ __forceinline__ float bflo(u32 u) { u32 t = u << 16; float f; __builtin_memcpy(&f, &t, 4); return f; }
__device__ __forceinline__ float bfhi(u32 u) { u32 t = u & 0xffff0000u; float f; __builtin_memcpy(&f, &t, 4); return f; }
__device__ __forceinline__ u16 f2bf(float f) {
  u32 u; __builtin_memcpy(&u, &f, 4);
  return (u16)((u + 0x7fffu + ((u >> 16) & 1u)) >> 16);
}

__device__ __forceinline__ void gload_lds16(const void* g, void* l) {
  __builtin_amdgcn_global_load_lds((const __attribute__((address_space(1))) void*)g,
                                   (__attribute__((address_space(3))) void*)l, 16, 0, 0);
}

// ---------------- transpose + fp32->bf16 pack: in [R][Cc] -> out [Cc][R] ----------------
__global__ __launch_bounds__(256)
void transpose_pack(const float* __restrict__ in, u16* __restrict__ out,
                    int R, int Cc, long in_bs, long out_bs)
{
  __shared__ float tile[32][33];
  in  += (size_t)blockIdx.z * in_bs;
  out += (size_t)blockIdx.z * out_bs;
  const int r0 = blockIdx.x * 32, c0 = blockIdx.y * 32;
  const int tx = threadIdx.x & 31, ty = threadIdx.x >> 5;   // 32 x 8
#pragma unroll
  for (int i = 0; i < 4; ++i) {
    int r = ty + i * 8;
    tile[r][tx] = in[(size_t)(r0 + r) * Cc + c0 + tx];
  }
  __syncthreads();
#pragma unroll
  for (int i = 0; i < 4; ++i) {
    int c = ty + i * 8;
    out[(size_t)(c0 + c) * R + r0 + tx] = f2bf(tile[tx][c]);
  }
}

// ---------------- LayerNorm fp32 -> bf16, C=1024, one block per row ----------------
__global__ __launch_bounds__(256)
void ln_f32_bf16(const float* __restrict__ x, const float* __restrict__ g,
                 const float* __restrict__ bta, u16* __restrict__ out)
{
  const int row = blockIdx.x, tid = threadIdx.x;
  const float4 v = ((const float4*)(x + (size_t)row * 1024))[tid];
  float s  = v.x + v.y + v.z + v.w;
  float ss = v.x * v.x + v.y * v.y + v.z * v.z + v.w * v.w;
#pragma unroll
  for (int m = 1; m < 64; m <<= 1) {
    s  += __shfl_xor(s, m);
    ss += __shfl_xor(ss, m);
  }
  __shared__ float red[8];
  const int wave = tid >> 6, lane = tid & 63;
  if (lane == 0) { red[wave] = s; red[4 + wave] = ss; }
  __syncthreads();
  s  = red[0] + red[1] + red[2] + red[3];
  ss = red[4] + red[5] + red[6] + red[7];
  const float mu  = s * (1.f / 1024.f);
  const float var = ss * (1.f / 1024.f) - mu * mu;
  const float rs  = rsqrtf(var + 1e-5f);
  const float4 gg = ((const float4*)g)[tid];
  const float4 bb = ((const float4*)bta)[tid];
  u32 w0 = (u32)f2bf((v.x - mu) * rs * gg.x + bb.x) | ((u32)f2bf((v.y - mu) * rs * gg.y + bb.y) << 16);
  u32 w1 = (u32)f2bf((v.z - mu) * rs * gg.z + bb.z) | ((u32)f2bf((v.w - mu) * rs * gg.w + bb.w) << 16);
  u32* outp = (u32*)(out + (size_t)row * 1024 + tid * 4);
  outp[0] = w0; outp[1] = w1;
}

// ---------------- 256x256 GEMM: row-half staging + counted-lgkmcnt MFMA ladder -------------
// LDS: A[2 buf][256 rows][64 K] + B same = 128 KiB, row stride 128B (full cache line).
// 8 waves (2Mx4N), acc[8][4]. Per tile t:
//   {stage A(t+1), stage B(t+1) (8 vmcnt ops, issued at TOP -> ~full-tile slack),
//    per half kh: issue 12 ds_read_b128 (bv0..3, av0..7) then LADDER:
//      rung m: s_waitcnt lgkmcnt(7-m); sched_barrier(0); 4 MFMA (av_m x bv0..3)
//    (DS ops retire in-order per wave -> counted waits valid; reads hide under MFMA),
//    vmcnt(0) (zero-stall: issued one tile ago), s_barrier}   -- ONE barrier per tile.
// Read swizzle: LDS[row][s] holds global seg s ^ ((row>>1)&7) -> conflict-free b128.
template <int EPI>
__global__ __launch_bounds__(512, 2)
void gemm8p(const u16* __restrict__ A, const u16* __restrict__ B, void* __restrict__ Cv,
            const float* __restrict__ bias, const float* __restrict__ resid,
            int M, int N, int K, int GM)
{
  __shared__ u16 lds[65536];   // A buf0 @0, A buf1 @16384, B buf0 @32768, B buf1 @49152 (u16)
  const int NT = K >> 6;
  const int tid = threadIdx.x;
  const int lane = tid & 63, wv = tid >> 6;
  const int wr = wv >> 2, wc = wv & 3;            // 2x4 wave grid
  const int r = lane & 15, kg = lane >> 4;

  // XCD-aware bijective swizzle (all grids divisible by 8), bn-major chunks
  const int nwg = gridDim.x;
  const int q = nwg >> 3;
  const int bid = blockIdx.x;
  const int sw = (bid & 7) * q + (bid >> 3);
  const int bn = sw / GM, bm = sw % GM;

  const u16* Ab = A + (size_t)bm * 256 * K;
  const u16* Bb = B + (size_t)bn * 256 * K;

  // byte addresses for asm ds_read_b128; seg(kh0)=kg^(r>>1), kh1 -> addr^64
  const u32 ldsb = (u32)(uintptr_t)lds;
  const u32 segb = (u32)((kg ^ (r >> 1)) << 4);
  const u32 abase = ldsb + (u32)((wr * 128 + r) * 128) + segb;            // + m*2048 imm, + buf*32768
  const u32 bbase = ldsb + 65536u + (u32)((wc * 64 + r) * 128) + segb;    // + n*2048 imm, + buf*32768

  f32x4 acc[8][4];
#pragma unroll
  for (int m = 0; m < 8; ++m)
#pragma unroll
    for (int n = 0; n < 4; ++n) acc[m][n] = f32x4{0.f, 0.f, 0.f, 0.f};

  // stage one row-half (128 rows x 64 K = 16KB): linear LDS dest, pre-swizzled global src
  auto stage = [&](const u16* src, int u, int h, int base_u16) {
#pragma unroll
    for (int jj = 0; jj < 2; ++jj) {
      int ci = jj * 512 + tid;
      int rl = ci >> 3;
      int sseg = (ci & 7) ^ ((rl >> 1) & 7);
      gload_lds16(src + (size_t)(h * 128 + rl) * K + u * 64 + sseg * 8,
                  &lds[base_u16 + h * 8192 + ci * 8]);
    }
  };

#define DSR(d, a, o) asm volatile("ds_read_b128 %0, %1 offset:" o : "=v"(d) : "v"(a))
#define ISSUE12(aR, bR) \
  DSR(bv0, bR, "0"); DSR(bv1, bR, "2048"); DSR(bv2, bR, "4096"); DSR(bv3, bR, "6144"); \
  DSR(av0, aR, "0"); DSR(av1, aR, "2048"); DSR(av2, aR, "4096"); DSR(av3, aR, "6144"); \
  DSR(av4, aR, "8192"); DSR(av5, aR, "10240"); DSR(av6, aR, "12288"); DSR(av7, aR, "14336")
#define MM(m, n) acc[m][n] = __builtin_amdgcn_mfma_f32_16x16x32_bf16(av##m, bv##n, acc[m][n], 0, 0, 0)
#define RUNG(m, cnt) \
  asm volatile("s_waitcnt lgkmcnt(" #cnt ")" ::: "memory"); \
  __builtin_amdgcn_sched_barrier(0); \
  MM(m, 0); MM(m, 1); MM(m, 2); MM(m, 3)
#define LADDER() \
  RUNG(0, 7); RUNG(1, 6); RUNG(2, 5); RUNG(3, 4); \
  RUNG(4, 3); RUNG(5, 2); RUNG(6, 1); RUNG(7, 0)

  // ---- prologue: full tile 0 -> buf0
  stage(Ab, 0, 0, 0);      stage(Ab, 0, 1, 0);
  stage(Bb, 0, 0, 32768);  stage(Bb, 0, 1, 32768);
  asm volatile("s_waitcnt vmcnt(0)" ::: "memory");
  __builtin_amdgcn_s_barrier();

  for (int t = 0; t < NT; ++t) {
    const int buf = t & 1;
    const bool s1 = (t + 1) < NT;
    const int nb = (buf ^ 1) * 16384;
    const u32 aA0 = abase + (u32)(buf * 32768);
    const u32 aB0 = bbase + (u32)(buf * 32768);
    const u32 aA1 = aA0 ^ 64u;
    const u32 aB1 = aB0 ^ 64u;

    // ---- all staging for t+1 issued up front (max vmcnt slack)
    if (s1) {
      stage(Ab, t + 1, 0, nb);           stage(Ab, t + 1, 1, nb);
      stage(Bb, t + 1, 0, 32768 + nb);   stage(Bb, t + 1, 1, 32768 + nb);
    }
    __builtin_amdgcn_sched_barrier(0);
    __builtin_amdgcn_s_setprio(1);
    // ---- half 0 (kh0): issue 12 reads, laddered MFMA
    {
      s16x8 av0, av1, av2, av3, av4, av5, av6, av7, bv0, bv1, bv2, bv3;
      ISSUE12(aA0, aB0);
      LADDER();
    }
    // ---- half 1 (kh1)
    {
      s16x8 av0, av1, av2, av3, av4, av5, av6, av7, bv0, bv1, bv2, bv3;
      ISSUE12(aA1, aB1);
      LADDER();
    }
    __builtin_amdgcn_s_setprio(0);
    __builtin_amdgcn_sched_barrier(0);
    asm volatile("s_waitcnt vmcnt(0)" ::: "memory");
    __builtin_amdgcn_s_barrier();
  }

  // ---- epilogue
#pragma unroll
  for (int m = 0; m < 8; ++m) {
#pragma unroll
    for (int n = 0; n < 4; ++n) {
#pragma unroll
      for (int j = 0; j < 4; ++j) {
        int row = bm * 256 + wr * 128 + m * 16 + kg * 4 + j;
        int col = bn * 256 + wc * 64 + n * 16 + r;
        size_t idx = (size_t)row * N + col;
        float v = acc[m][n][j];
        if constexpr (EPI == 0) {
          ((u16*)Cv)[idx] = f2bf(v);
        } else if constexpr (EPI == 1) {
          ((float*)Cv)[idx] = v + bias[col] + resid[idx];
        } else if constexpr (EPI == 2) {
          ((u16*)Cv)[idx] = f2bf(fmaxf(v + bias[col], 0.f));
        } else {
          ((float*)Cv)[idx] = v + bias[col] + resid[idx];
        }
      }
    }
  }
#undef DSR
#undef ISSUE12
#undef MM
#undef RUNG
#undef LADDER
}

// ---------------- MFMA flash attention: one block per (b,h), 4 waves, wave w = 64 q-rows ----
__global__ __launch_bounds__(256)
void attn_mfma(const u16* __restrict__ qkv, u16* __restrict__ outc)
{
  const int bh = blockIdx.x, b = bh >> 4, h = bh & 15;
  const int tid = threadIdx.x;
  const int lane = tid & 63, w = tid >> 6;
  const int r = lane & 15, kg = lane >> 4;

  __shared__ u16 Ks[64 * 64];       // swizzled chunks
  __shared__ u16 Vt[64 * 72];       // [d][key], stride 72
  __shared__ u16 P[4][64 * 72];     // per-wave P, [qrow][key], stride 72

  const u16* qbase = qkv + (size_t)(b * 256) * 3072 + h * 64;

  s16x8 qf[4][2];
#pragma unroll
  for (int m = 0; m < 4; ++m)
#pragma unroll
    for (int ks = 0; ks < 2; ++ks)
      qf[m][ks] = *(const s16x8*)(qbase + (size_t)(w * 64 + m * 16 + r) * 3072 + ks * 32 + kg * 8);

  f32x4 of[4][4];
  float mrun[4][4], lrun[4][4];
#pragma unroll
  for (int m = 0; m < 4; ++m) {
#pragma unroll
    for (int n = 0; n < 4; ++n) of[m][n] = f32x4{0.f, 0.f, 0.f, 0.f};
#pragma unroll
    for (int j = 0; j < 4; ++j) { mrun[m][j] = -1e30f; lrun[m][j] = 0.f; }
  }

  const float cexp = 0.03125f * 1.4426950408889634f;

  for (int kt = 0; kt < 4; ++kt) {
#pragma unroll
    for (int jj = 0; jj < 2; ++jj) {
      int ci = jj * 256 + tid;
      int key = ci >> 3, seg = ci & 7;
      int sseg = seg ^ (key & 7);
      gload_lds16(qkv + (size_t)(b * 256 + kt * 64 + key) * 3072 + 1024 + h * 64 + sseg * 8,
                  &Ks[ci * 8]);
    }
    {
      int row = tid >> 2, q = tid & 3;
      const u16* vg = qkv + (size_t)(b * 256 + kt * 64 + row) * 3072 + 2048 + h * 64 + q * 16;
      union { uint4 u[2]; u16 s[16]; } vv;
      vv.u[0] = *(const uint4*)vg;
      vv.u[1] = *(const uint4*)(vg + 8);
#pragma unroll
      for (int i = 0; i < 16; ++i)
        Vt[(q * 16 + i) * 72 + row] = vv.s[i];
    }
    __syncthreads();

    if (w >= kt) {
      f32x4 s[4][4];
#pragma unroll
      for (int m = 0; m < 4; ++m)
#pragma unroll
        for (int n = 0; n < 4; ++n) s[m][n] = f32x4{0.f, 0.f, 0.f, 0.f};
#pragma unroll
      for (int ks = 0; ks < 2; ++ks) {
        s16x8 kb[4];
#pragma unroll
        for (int n = 0; n < 4; ++n) {
          int row = n * 16 + r;
          int sseg = (ks * 4 + kg) ^ (row & 7);
          kb[n] = *(const s16x8*)&Ks[row * 64 + sseg * 8];
        }
#pragma unroll
        for (int m = 0; m < 4; ++m)
#pragma unroll
          for (int n = 0; n < 4; ++n)
            s[m][n] = __builtin_amdgcn_mfma_f32_16x16x32_bf16(qf[m][ks], kb[n], s[m][n], 0, 0, 0);
      }
      if (kt == w) {
#pragma unroll
        for (int m = 0; m < 4; ++m)
#pragma unroll
          for (int n = 0; n < 4; ++n)
#pragma unroll
            for (int j = 0; j < 4; ++j)
              if (n * 16 + r > m * 16 + kg * 4 + j) s[m][n][j] = -1e30f;
      }
#pragma unroll
      for (int m = 0; m < 4; ++m) {
        float rm[4], rsc[4], ls[4];
#pragma unroll
        for (int j = 0; j < 4; ++j) {
          rm[j] = fmaxf(fmaxf(s[m][0][j], s[m][1][j]), fmaxf(s[m][2][j], s[m][3][j]));
          rm[j] = fmaxf(rm[j], __shfl_xor(rm[j], 1));
          rm[j] = fmaxf(rm[j], __shfl_xor(rm[j], 2));
          rm[j] = fmaxf(rm[j], __shfl_xor(rm[j], 4));
          rm[j] = fmaxf(rm[j], __shfl_xor(rm[j], 8));
          float mnew = fmaxf(mrun[m][j], rm[j]);
          rsc[j] = exp2f((mrun[m][j] - mnew) * cexp);
          mrun[m][j] = mnew;
          ls[j] = 0.f;
        }
#pragma unroll
        for (int n = 0; n < 4; ++n)
#pragma unroll
          for (int j = 0; j < 4; ++j) {
            float p = exp2f((s[m][n][j] - mrun[m][j]) * cexp);
            ls[j] += p;
            P[w][(m * 16 + kg * 4 + j) * 72 + n * 16 + r] = f2bf(p);
          }
#pragma unroll
        for (int j = 0; j < 4; ++j) {
          ls[j] += __shfl_xor(ls[j], 1);
          ls[j] += __shfl_xor(ls[j], 2);
          ls[j] += __shfl_xor(ls[j], 4);
          ls[j] += __shfl_xor(ls[j], 8);
          lrun[m][j] = lrun[m][j] * rsc[j] + ls[j];
        }
#pragma unroll
        for (int n = 0; n < 4; ++n)
#pragma unroll
          for (int j = 0; j < 4; ++j)
            of[m][n][j] *= rsc[j];
      }
#pragma unroll
      for (int kk = 0; kk < 2; ++kk) {
        s16x8 pa[4], vb[4];
#pragma unroll
        for (int m = 0; m < 4; ++m)
          pa[m] = *(const s16x8*)&P[w][(m * 16 + r) * 72 + kk * 32 + kg * 8];
#pragma unroll
        for (int n = 0; n < 4; ++n)
          vb[n] = *(const s16x8*)&Vt[(n * 16 + r) * 72 + kk * 32 + kg * 8];
#pragma unroll
        for (int m = 0; m < 4; ++m)
#pragma unroll
          for (int n = 0; n < 4; ++n)
            of[m][n] = __builtin_amdgcn_mfma_f32_16x16x32_bf16(pa[m], vb[n], of[m][n], 0, 0, 0);
      }
    }
    __syncthreads();
  }

#pragma unroll
  for (int m = 0; m < 4; ++m) {
    float inv[4];
#pragma unroll
    for (int j = 0; j < 4; ++j) inv[j] = 1.f / lrun[m][j];
#pragma unroll
    for (int n = 0; n < 4; ++n)
#pragma unroll
      for (int j = 0; j < 4; ++j) {
        int row = b * 256 + w * 64 + m * 16 + kg * 4 + j;
        outc[(size_t)row * 1024 + h * 64 + n * 16 + r] = f2bf(of[m][n][j] * inv[j]);
      }
  }
}

// ------------------------------------------------------------------------------------------
extern "C" void kernel_launch(void* const* d_in, const int* in_sizes, int n_in,
                              void* d_out, int out_size, void* d_ws, size_t ws_size,
                              hipStream_t stream) {
  (void)in_sizes; (void)n_in; (void)out_size; (void)ws_size;
  const float* x     = (const float*)d_in[0];
  const float* Wq    = (const float*)d_in[1];
  const float* Wk    = (const float*)d_in[2];
  const float* Wv    = (const float*)d_in[3];
  const float* Wproj = (const float*)d_in[4];
  const float* bproj = (const float*)d_in[5];
  const float* W1    = (const float*)d_in[6];
  const float* b1    = (const float*)d_in[7];
  const float* W2    = (const float*)d_in[8];
  const float* b2    = (const float*)d_in[9];
  const float* ln1g  = (const float*)d_in[10];
  const float* ln1b  = (const float*)d_in[11];
  const float* ln2g  = (const float*)d_in[12];
  const float* ln2b  = (const float*)d_in[13];
  float* out = (float*)d_out;

  char* ws = (char*)d_ws;
  u16*   WqkvT  = (u16*)(ws + 0);              // [3072][1024] bf16
  u16*   WprojT = (u16*)(ws + 6291456);        // [1024][1024]
  u16*   W1T    = (u16*)(ws + 8388608);        // [4096][1024]
  u16*   W2T    = (u16*)(ws + 16777216);       // [1024][4096]
  u16*   hb     = (u16*)(ws + 25165824);       // [16384][1024] LN1 out; later reused as attnout
  u16*   qkvb   = (u16*)(ws + 58720256);       // [16384][3072]
  float* x2     = (float*)(ws + 159383552);    // [16384][1024] f32
  u16*   h2     = (u16*)(ws + 226492416);      // [16384][1024]
  u16*   ffn1   = (u16*)(ws + 25165824);       // [16384][4096] overlays hb+qkvb (both dead by then)
  u16*   attnout = hb;

  const int M = 16384;

  transpose_pack<<<dim3(32, 2, 16), 256, 0, stream>>>(Wq, WqkvT,           1024, 64, 65536, 65536);
  transpose_pack<<<dim3(32, 2, 16), 256, 0, stream>>>(Wk, WqkvT + 1048576, 1024, 64, 65536, 65536);
  transpose_pack<<<dim3(32, 2, 16), 256, 0, stream>>>(Wv, WqkvT + 2097152, 1024, 64, 65536, 65536);
  transpose_pack<<<dim3(32, 32, 1), 256, 0, stream>>>(Wproj, WprojT, 1024, 1024, 0, 0);
  transpose_pack<<<dim3(32, 128, 1), 256, 0, stream>>>(W1, W1T, 1024, 4096, 0, 0);
  transpose_pack<<<dim3(128, 32, 1), 256, 0, stream>>>(W2, W2T, 4096, 1024, 0, 0);

  ln_f32_bf16<<<M, 256, 0, stream>>>(x, ln1g, ln1b, hb);

  // QKV: [16384,1024] x [3072,1024]^T -> bf16 ; grid = GM*GN = 64*12
  gemm8p<0><<<64 * 12, 512, 0, stream>>>(hb, WqkvT, qkvb, nullptr, nullptr, M, 3072, 1024, 64);

  attn_mfma<<<1024, 256, 0, stream>>>(qkvb, attnout);

  // proj + bias + residual(x) -> x2 f32 ; grid 64*4
  gemm8p<1><<<64 * 4, 512, 0, stream>>>(attnout, WprojT, x2, bproj, x, M, 1024, 1024, 64);

  ln_f32_bf16<<<M, 256, 0, stream>>>(x2, ln2g, ln2b, h2);

  // FFN1: relu(h2 @ W1 + b1) -> bf16 ; grid 64*16
  gemm8p<2><<<64 * 16, 512, 0, stream>>>(h2, W1T, ffn1, b1, nullptr, M, 4096, 1024, 64);

  // FFN2: ffn1 @ W2 + b2 + x2 -> out f32 ; grid 64*4
  gemm8p<3><<<64 * 4, 512, 0, stream>>>(ffn1, W2T, out, b2, x2, M, 1024, 4096, 64);
}

// Round 7
// 557.110 us; speedup vs baseline: 1.1111x; 1.1111x over previous
//
#include <hip/hip_runtime.h>
#include <stdint.h>

using u16 = unsigned short;
using u32 = unsigned int;

typedef __attribute__((ext_vector_type(8))) short s16x8;
typedef __attribute__((ext_vector_type(4))) float f32x4;

__device__ __forceinline__ float bf2f(u16 u) { u32 t = (u32)u << 16; float f; __builtin_memcpy(&f, &t, 4); return f; }
__device__ __forceinline__ u16 f2bf(float f) {
  u32 u; __builtin_memcpy(&u, &f, 4);
  return (u16)((u + 0x7fffu + ((u >> 16) & 1u)) >> 16);
}

__device__ __forceinline__ void gload_lds16(const void* g, void* l) {
  __builtin_amdgcn_global_load_lds((const __attribute__((address_space(1))) void*)g,
                                   (__attribute__((address_space(3))) void*)l, 16, 0, 0);
}

// ---------------- transpose + fp32->bf16 pack: in [R][Cc] -> out [Cc][R] ----------------
__global__ __launch_bounds__(256)
void transpose_pack(const float* __restrict__ in, u16* __restrict__ out,
                    int R, int Cc, long in_bs, long out_bs)
{
  __shared__ float tile[32][33];
  in  += (size_t)blockIdx.z * in_bs;
  out += (size_t)blockIdx.z * out_bs;
  const int r0 = blockIdx.x * 32, c0 = blockIdx.y * 32;
  const int tx = threadIdx.x & 31, ty = threadIdx.x >> 5;   // 32 x 8
#pragma unroll
  for (int i = 0; i < 4; ++i) {
    int r = ty + i * 8;
    tile[r][tx] = in[(size_t)(r0 + r) * Cc + c0 + tx];
  }
  __syncthreads();
#pragma unroll
  for (int i = 0; i < 4; ++i) {
    int c = ty + i * 8;
    out[(size_t)(c0 + c) * R + r0 + tx] = f2bf(tile[tx][c]);
  }
}

// ---------------- LayerNorm -> bf16, C=1024, one block per row; IN: 0=f32, 1=bf16 --------
template <int IN>
__global__ __launch_bounds__(256)
void ln_to_bf16(const void* __restrict__ xv, const float* __restrict__ g,
                const float* __restrict__ bta, u16* __restrict__ out)
{
  const int row = blockIdx.x, tid = threadIdx.x;
  float4 v;
  if constexpr (IN == 0) {
    v = ((const float4*)((const float*)xv + (size_t)row * 1024))[tid];
  } else {
    uint2 u = ((const uint2*)((const u16*)xv + (size_t)row * 1024))[tid];
    v.x = bf2f((u16)(u.x & 0xffff)); v.y = bf2f((u16)(u.x >> 16));
    v.z = bf2f((u16)(u.y & 0xffff)); v.w = bf2f((u16)(u.y >> 16));
  }
  float s  = v.x + v.y + v.z + v.w;
  float ss = v.x * v.x + v.y * v.y + v.z * v.z + v.w * v.w;
#pragma unroll
  for (int m = 1; m < 64; m <<= 1) {
    s  += __shfl_xor(s, m);
    ss += __shfl_xor(ss, m);
  }
  __shared__ float red[8];
  const int wave = tid >> 6, lane = tid & 63;
  if (lane == 0) { red[wave] = s; red[4 + wave] = ss; }
  __syncthreads();
  s  = red[0] + red[1] + red[2] + red[3];
  ss = red[4] + red[5] + red[6] + red[7];
  const float mu  = s * (1.f / 1024.f);
  const float var = ss * (1.f / 1024.f) - mu * mu;
  const float rs  = rsqrtf(var + 1e-5f);
  const float4 gg = ((const float4*)g)[tid];
  const float4 bb = ((const float4*)bta)[tid];
  u32 w0 = (u32)f2bf((v.x - mu) * rs * gg.x + bb.x) | ((u32)f2bf((v.y - mu) * rs * gg.y + bb.y) << 16);
  u32 w1 = (u32)f2bf((v.z - mu) * rs * gg.z + bb.z) | ((u32)f2bf((v.w - mu) * rs * gg.w + bb.w) << 16);
  u32* outp = (u32*)(out + (size_t)row * 1024 + tid * 4);
  outp[0] = w0; outp[1] = w1;
}

// ---------------- 256x256 GEMM: row-half staging + counted-lgkmcnt MFMA ladder -------------
// K-loop identical to round 6 (proven). New: XCD rectangle chunking — XCD x owns a CM x CN
// rect of the (GM,GN) block grid, ordered bn-fastest, so concurrent blocks per XCD form a
// ~4bm x 8bn rect whose K-windows fit L2 and are shared 4-8 ways (FETCH cut).
// EPI 0: bf16(acc)   1: bf16(acc+bias+resid_f32)   2: bf16 relu(acc+bias)   3: f32 acc+bias+resid_bf16
template <int EPI>
__global__ __launch_bounds__(512, 2)
void gemm8p(const u16* __restrict__ A, const u16* __restrict__ B, void* __restrict__ Cv,
            const float* __restrict__ bias, const void* __restrict__ resid,
            int M, int N, int K, int CM, int CN, int XN)
{
  __shared__ u16 lds[65536];   // A buf0 @0, A buf1 @16384, B buf0 @32768, B buf1 @49152 (u16)
  const int NT = K >> 6;
  const int tid = threadIdx.x;
  const int lane = tid & 63, wv = tid >> 6;
  const int wr = wv >> 2, wc = wv & 3;            // 2x4 wave grid
  const int r = lane & 15, kg = lane >> 4;

  // XCD rectangle chunking (bijective: CM*CN*8 == gridDim.x, GM=CM*(8/XN), GN=CN*XN)
  const int bid = blockIdx.x;
  const int x = bid & 7, i = bid >> 3;
  const int bm = (x / XN) * CM + i / CN;
  const int bn = (x % XN) * CN + i % CN;

  const u16* Ab = A + (size_t)bm * 256 * K;
  const u16* Bb = B + (size_t)bn * 256 * K;

  // byte addresses for asm ds_read_b128; seg(kh0)=kg^(r>>1), kh1 -> addr^64
  const u32 ldsb = (u32)(uintptr_t)lds;
  const u32 segb = (u32)((kg ^ (r >> 1)) << 4);
  const u32 abase = ldsb + (u32)((wr * 128 + r) * 128) + segb;            // + m*2048 imm, + buf*32768
  const u32 bbase = ldsb + 65536u + (u32)((wc * 64 + r) * 128) + segb;    // + n*2048 imm, + buf*32768

  f32x4 acc[8][4];
#pragma unroll
  for (int m = 0; m < 8; ++m)
#pragma unroll
    for (int n = 0; n < 4; ++n) acc[m][n] = f32x4{0.f, 0.f, 0.f, 0.f};

  // stage one row-half (128 rows x 64 K = 16KB): linear LDS dest, pre-swizzled global src
  auto stage = [&](const u16* src, int u, int h, int base_u16) {
#pragma unroll
    for (int jj = 0; jj < 2; ++jj) {
      int ci = jj * 512 + tid;
      int rl = ci >> 3;
      int sseg = (ci & 7) ^ ((rl >> 1) & 7);
      gload_lds16(src + (size_t)(h * 128 + rl) * K + u * 64 + sseg * 8,
                  &lds[base_u16 + h * 8192 + ci * 8]);
    }
  };

#define DSR(d, a, o) asm volatile("ds_read_b128 %0, %1 offset:" o : "=v"(d) : "v"(a))
#define ISSUE12(aR, bR) \
  DSR(bv0, bR, "0"); DSR(bv1, bR, "2048"); DSR(bv2, bR, "4096"); DSR(bv3, bR, "6144"); \
  DSR(av0, aR, "0"); DSR(av1, aR, "2048"); DSR(av2, aR, "4096"); DSR(av3, aR, "6144"); \
  DSR(av4, aR, "8192"); DSR(av5, aR, "10240"); DSR(av6, aR, "12288"); DSR(av7, aR, "14336")
#define MM(m, n) acc[m][n] = __builtin_amdgcn_mfma_f32_16x16x32_bf16(av##m, bv##n, acc[m][n], 0, 0, 0)
#define RUNG(m, cnt) \
  asm volatile("s_waitcnt lgkmcnt(" #cnt ")" ::: "memory"); \
  __builtin_amdgcn_sched_barrier(0); \
  MM(m, 0); MM(m, 1); MM(m, 2); MM(m, 3)
#define LADDER() \
  RUNG(0, 7); RUNG(1, 6); RUNG(2, 5); RUNG(3, 4); \
  RUNG(4, 3); RUNG(5, 2); RUNG(6, 1); RUNG(7, 0)

  // ---- prologue: full tile 0 -> buf0
  stage(Ab, 0, 0, 0);      stage(Ab, 0, 1, 0);
  stage(Bb, 0, 0, 32768);  stage(Bb, 0, 1, 32768);
  asm volatile("s_waitcnt vmcnt(0)" ::: "memory");
  __builtin_amdgcn_s_barrier();

  for (int t = 0; t < NT; ++t) {
    const int buf = t & 1;
    const bool s1 = (t + 1) < NT;
    const int nb = (buf ^ 1) * 16384;
    const u32 aA0 = abase + (u32)(buf * 32768);
    const u32 aB0 = bbase + (u32)(buf * 32768);
    const u32 aA1 = aA0 ^ 64u;
    const u32 aB1 = aB0 ^ 64u;

    // ---- all staging for t+1 issued up front (max vmcnt slack)
    if (s1) {
      stage(Ab, t + 1, 0, nb);           stage(Ab, t + 1, 1, nb);
      stage(Bb, t + 1, 0, 32768 + nb);   stage(Bb, t + 1, 1, 32768 + nb);
    }
    __builtin_amdgcn_sched_barrier(0);
    __builtin_amdgcn_s_setprio(1);
    // ---- half 0 (kh0): issue 12 reads, laddered MFMA
    {
      s16x8 av0, av1, av2, av3, av4, av5, av6, av7, bv0, bv1, bv2, bv3;
      ISSUE12(aA0, aB0);
      LADDER();
    }
    // ---- half 1 (kh1)
    {
      s16x8 av0, av1, av2, av3, av4, av5, av6, av7, bv0, bv1, bv2, bv3;
      ISSUE12(aA1, aB1);
      LADDER();
    }
    __builtin_amdgcn_s_setprio(0);
    __builtin_amdgcn_sched_barrier(0);
    asm volatile("s_waitcnt vmcnt(0)" ::: "memory");
    __builtin_amdgcn_s_barrier();
  }

  // ---- epilogue
#pragma unroll
  for (int m = 0; m < 8; ++m) {
#pragma unroll
    for (int n = 0; n < 4; ++n) {
#pragma unroll
      for (int j = 0; j < 4; ++j) {
        int row = bm * 256 + wr * 128 + m * 16 + kg * 4 + j;
        int col = bn * 256 + wc * 64 + n * 16 + r;
        size_t idx = (size_t)row * N + col;
        float v = acc[m][n][j];
        if constexpr (EPI == 0) {
          ((u16*)Cv)[idx] = f2bf(v);
        } else if constexpr (EPI == 1) {
          ((u16*)Cv)[idx] = f2bf(v + bias[col] + ((const float*)resid)[idx]);
        } else if constexpr (EPI == 2) {
          ((u16*)Cv)[idx] = f2bf(fmaxf(v + bias[col], 0.f));
        } else {
          ((float*)Cv)[idx] = v + bias[col] + bf2f(((const u16*)resid)[idx]);
        }
      }
    }
  }
#undef DSR
#undef ISSUE12
#undef MM
#undef RUNG
#undef LADDER
}

// ---------------- MFMA flash attention: one block per (b,h), 4 waves, wave w = 64 q-rows ----
__global__ __launch_bounds__(256)
void attn_mfma(const u16* __restrict__ qkv, u16* __restrict__ outc)
{
  const int bh = blockIdx.x, b = bh >> 4, h = bh & 15;
  const int tid = threadIdx.x;
  const int lane = tid & 63, w = tid >> 6;
  const int r = lane & 15, kg = lane >> 4;

  __shared__ u16 Ks[64 * 64];       // swizzled chunks
  __shared__ u16 Vt[64 * 72];       // [d][key], stride 72
  __shared__ u16 P[4][64 * 72];     // per-wave P, [qrow][key], stride 72

  const u16* qbase = qkv + (size_t)(b * 256) * 3072 + h * 64;

  s16x8 qf[4][2];
#pragma unroll
  for (int m = 0; m < 4; ++m)
#pragma unroll
    for (int ks = 0; ks < 2; ++ks)
      qf[m][ks] = *(const s16x8*)(qbase + (size_t)(w * 64 + m * 16 + r) * 3072 + ks * 32 + kg * 8);

  f32x4 of[4][4];
  float mrun[4][4], lrun[4][4];
#pragma unroll
  for (int m = 0; m < 4; ++m) {
#pragma unroll
    for (int n = 0; n < 4; ++n) of[m][n] = f32x4{0.f, 0.f, 0.f, 0.f};
#pragma unroll
    for (int j = 0; j < 4; ++j) { mrun[m][j] = -1e30f; lrun[m][j] = 0.f; }
  }

  const float cexp = 0.03125f * 1.4426950408889634f;

  for (int kt = 0; kt < 4; ++kt) {
#pragma unroll
    for (int jj = 0; jj < 2; ++jj) {
      int ci = jj * 256 + tid;
      int key = ci >> 3, seg = ci & 7;
      int sseg = seg ^ (key & 7);
      gload_lds16(qkv + (size_t)(b * 256 + kt * 64 + key) * 3072 + 1024 + h * 64 + sseg * 8,
                  &Ks[ci * 8]);
    }
    {
      int row = tid >> 2, q = tid & 3;
      const u16* vg = qkv + (size_t)(b * 256 + kt * 64 + row) * 3072 + 2048 + h * 64 + q * 16;
      union { uint4 u[2]; u16 s[16]; } vv;
      vv.u[0] = *(const uint4*)vg;
      vv.u[1] = *(const uint4*)(vg + 8);
#pragma unroll
      for (int i = 0; i < 16; ++i)
        Vt[(q * 16 + i) * 72 + row] = vv.s[i];
    }
    __syncthreads();

    if (w >= kt) {
      f32x4 s[4][4];
#pragma unroll
      for (int m = 0; m < 4; ++m)
#pragma unroll
        for (int n = 0; n < 4; ++n) s[m][n] = f32x4{0.f, 0.f, 0.f, 0.f};
#pragma unroll
      for (int ks = 0; ks < 2; ++ks) {
        s16x8 kb[4];
#pragma unroll
        for (int n = 0; n < 4; ++n) {
          int row = n * 16 + r;
          int sseg = (ks * 4 + kg) ^ (row & 7);
          kb[n] = *(const s16x8*)&Ks[row * 64 + sseg * 8];
        }
#pragma unroll
        for (int m = 0; m < 4; ++m)
#pragma unroll
          for (int n = 0; n < 4; ++n)
            s[m][n] = __builtin_amdgcn_mfma_f32_16x16x32_bf16(qf[m][ks], kb[n], s[m][n], 0, 0, 0);
      }
      if (kt == w) {
#pragma unroll
        for (int m = 0; m < 4; ++m)
#pragma unroll
          for (int n = 0; n < 4; ++n)
#pragma unroll
            for (int j = 0; j < 4; ++j)
              if (n * 16 + r > m * 16 + kg * 4 + j) s[m][n][j] = -1e30f;
      }
#pragma unroll
      for (int m = 0; m < 4; ++m) {
        float rm[4], rsc[4], ls[4];
#pragma unroll
        for (int j = 0; j < 4; ++j) {
          rm[j] = fmaxf(fmaxf(s[m][0][j], s[m][1][j]), fmaxf(s[m][2][j], s[m][3][j]));
          rm[j] = fmaxf(rm[j], __shfl_xor(rm[j], 1));
          rm[j] = fmaxf(rm[j], __shfl_xor(rm[j], 2));
          rm[j] = fmaxf(rm[j], __shfl_xor(rm[j], 4));
          rm[j] = fmaxf(rm[j], __shfl_xor(rm[j], 8));
          float mnew = fmaxf(mrun[m][j], rm[j]);
          rsc[j] = exp2f((mrun[m][j] - mnew) * cexp);
          mrun[m][j] = mnew;
          ls[j] = 0.f;
        }
#pragma unroll
        for (int n = 0; n < 4; ++n)
#pragma unroll
          for (int j = 0; j < 4; ++j) {
            float p = exp2f((s[m][n][j] - mrun[m][j]) * cexp);
            ls[j] += p;
            P[w][(m * 16 + kg * 4 + j) * 72 + n * 16 + r] = f2bf(p);
          }
#pragma unroll
        for (int j = 0; j < 4; ++j) {
          ls[j] += __shfl_xor(ls[j], 1);
          ls[j] += __shfl_xor(ls[j], 2);
          ls[j] += __shfl_xor(ls[j], 4);
          ls[j] += __shfl_xor(ls[j], 8);
          lrun[m][j] = lrun[m][j] * rsc[j] + ls[j];
        }
#pragma unroll
        for (int n = 0; n < 4; ++n)
#pragma unroll
          for (int j = 0; j < 4; ++j)
            of[m][n][j] *= rsc[j];
      }
#pragma unroll
      for (int kk = 0; kk < 2; ++kk) {
        s16x8 pa[4], vb[4];
#pragma unroll
        for (int m = 0; m < 4; ++m)
          pa[m] = *(const s16x8*)&P[w][(m * 16 + r) * 72 + kk * 32 + kg * 8];
#pragma unroll
        for (int n = 0; n < 4; ++n)
          vb[n] = *(const s16x8*)&Vt[(n * 16 + r) * 72 + kk * 32 + kg * 8];
#pragma unroll
        for (int m = 0; m < 4; ++m)
#pragma unroll
          for (int n = 0; n < 4; ++n)
            of[m][n] = __builtin_amdgcn_mfma_f32_16x16x32_bf16(pa[m], vb[n], of[m][n], 0, 0, 0);
      }
    }
    __syncthreads();
  }

#pragma unroll
  for (int m = 0; m < 4; ++m) {
    float inv[4];
#pragma unroll
    for (int j = 0; j < 4; ++j) inv[j] = 1.f / lrun[m][j];
#pragma unroll
    for (int n = 0; n < 4; ++n)
#pragma unroll
      for (int j = 0; j < 4; ++j) {
        int row = b * 256 + w * 64 + m * 16 + kg * 4 + j;
        outc[(size_t)row * 1024 + h * 64 + n * 16 + r] = f2bf(of[m][n][j] * inv[j]);
      }
  }
}

// ------------------------------------------------------------------------------------------
extern "C" void kernel_launch(void* const* d_in, const int* in_sizes, int n_in,
                              void* d_out, int out_size, void* d_ws, size_t ws_size,
                              hipStream_t stream) {
  (void)in_sizes; (void)n_in; (void)out_size; (void)ws_size;
  const float* x     = (const float*)d_in[0];
  const float* Wq    = (const float*)d_in[1];
  const float* Wk    = (const float*)d_in[2];
  const float* Wv    = (const float*)d_in[3];
  const float* Wproj = (const float*)d_in[4];
  const float* bproj = (const float*)d_in[5];
  const float* W1    = (const float*)d_in[6];
  const float* b1    = (const float*)d_in[7];
  const float* W2    = (const float*)d_in[8];
  const float* b2    = (const float*)d_in[9];
  const float* ln1g  = (const float*)d_in[10];
  const float* ln1b  = (const float*)d_in[11];
  const float* ln2g  = (const float*)d_in[12];
  const float* ln2b  = (const float*)d_in[13];
  float* out = (float*)d_out;

  char* ws = (char*)d_ws;
  u16*   WqkvT  = (u16*)(ws + 0);              // [3072][1024] bf16
  u16*   WprojT = (u16*)(ws + 6291456);        // [1024][1024]
  u16*   W1T    = (u16*)(ws + 8388608);        // [4096][1024]
  u16*   W2T    = (u16*)(ws + 16777216);       // [1024][4096]
  u16*   hb     = (u16*)(ws + 25165824);       // [16384][1024] LN1 out; later reused as attnout
  u16*   qkvb   = (u16*)(ws + 58720256);       // [16384][3072]
  u16*   x2     = (u16*)(ws + 159383552);      // [16384][1024] bf16 residual stream
  u16*   h2     = (u16*)(ws + 226492416);      // [16384][1024]
  u16*   ffn1   = (u16*)(ws + 25165824);       // [16384][4096] overlays hb+qkvb (both dead by then)
  u16*   attnout = hb;

  const int M = 16384;

  transpose_pack<<<dim3(32, 2, 16), 256, 0, stream>>>(Wq, WqkvT,           1024, 64, 65536, 65536);
  transpose_pack<<<dim3(32, 2, 16), 256, 0, stream>>>(Wk, WqkvT + 1048576, 1024, 64, 65536, 65536);
  transpose_pack<<<dim3(32, 2, 16), 256, 0, stream>>>(Wv, WqkvT + 2097152, 1024, 64, 65536, 65536);
  transpose_pack<<<dim3(32, 32, 1), 256, 0, stream>>>(Wproj, WprojT, 1024, 1024, 0, 0);
  transpose_pack<<<dim3(32, 128, 1), 256, 0, stream>>>(W1, W1T, 1024, 4096, 0, 0);
  transpose_pack<<<dim3(128, 32, 1), 256, 0, stream>>>(W2, W2T, 4096, 1024, 0, 0);

  ln_to_bf16<0><<<M, 256, 0, stream>>>(x, ln1g, ln1b, hb);

  // QKV: GM=64, GN=12 ; XCD rect 16x6 (XN=2)
  gemm8p<0><<<768, 512, 0, stream>>>(hb, WqkvT, qkvb, nullptr, nullptr, M, 3072, 1024, 16, 6, 2);

  attn_mfma<<<1024, 256, 0, stream>>>(qkvb, attnout);

  // proj + bias + residual(x f32) -> x2 bf16 ; GM=64, GN=4 ; rect 8x4 (XN=1)
  gemm8p<1><<<256, 512, 0, stream>>>(attnout, WprojT, x2, bproj, x, M, 1024, 1024, 8, 4, 1);

  ln_to_bf16<1><<<M, 256, 0, stream>>>(x2, ln2g, ln2b, h2);

  // FFN1: relu(h2 @ W1 + b1) -> bf16 ; GM=64, GN=16 ; rect 16x8 (XN=2)
  gemm8p<2><<<1024, 512, 0, stream>>>(h2, W1T, ffn1, b1, nullptr, M, 4096, 1024, 16, 8, 2);

  // FFN2: ffn1 @ W2 + b2 + x2(bf16) -> out f32 ; GM=64, GN=4 ; rect 8x4 (XN=1)
  gemm8p<3><<<256, 512, 0, stream>>>(ffn1, W2T, out, b2, x2, M, 1024, 4096, 8, 4, 1);
}